// Round 5
// baseline (398.751 us; speedup 1.0000x reference)
//
#include <hip/hip_runtime.h>

#define TT 512

typedef __attribute__((ext_vector_type(8))) short short8;
typedef __attribute__((ext_vector_type(4))) float floatx4;

__device__ __forceinline__ unsigned short f2bf(float f) {  // RTNE (weights only)
    unsigned u = __float_as_uint(f);
    return (unsigned short)((u + 0x7FFFu + ((u >> 16) & 1u)) >> 16);
}
__device__ __forceinline__ float bf2f(unsigned short b) {
    return __uint_as_float(((unsigned)b) << 16);
}
// tanh(z) = 1 - 2/(exp(2z)+1); endpoints exact without clamp
__device__ __forceinline__ float fast_tanh(float z) {
    const float e = __expf(2.f * z);
    return 1.f - __fdividef(2.f, e + 1.f);
}
__device__ __forceinline__ float f4e(const float4& v, int r) {
    return (r == 0) ? v.x : (r == 1) ? v.y : (r == 2) ? v.z : v.w;
}

// Layer-pipelined MFMA RNN, one barrier per superstep, 2x-unrolled so all
// LDS buffer indices are compile-time (addresses = base + immediate offset).
// Superstep s: h0(s)   = tanh(W0·h0(s-1) + x(s)·Wih0 + b0)
//              h1(s-1) = tanh(Wi1·h0(s-1) + W1·h1(s-2) + b1)
// h planes in LDS, chunked layout [chunk][batch][8] (conflict-free b128 reads).
// Split-3 bf16 (Whi*hhi + Whi*hlo + Wlo*hhi) ~ fp32; h split by truncation.
__global__ void __launch_bounds__(256, 1)
rnn2_mfma(const float* __restrict__ x,
          const float* __restrict__ W_ih0, const float* __restrict__ W_hh0,
          const float* __restrict__ b_ih0, const float* __restrict__ b_hh0,
          const float* __restrict__ W_ih1, const float* __restrict__ W_hh1,
          const float* __restrict__ b_ih1, const float* __restrict__ b_hh1,
          const float* __restrict__ W_fc, const float* __restrict__ b_fc,
          float* __restrict__ out)
{
    __shared__ short h0p[2][2][1024];  // [buf][part hi/lo][chunk*512 + 128q + 8n]
    __shared__ short h1p[2][2][1024];
    __shared__ float red[4][16];

    const int tid = threadIdx.x;
    const int lane = tid & 63;
    const int w = tid >> 6;
    const int n = lane & 15;
    const int q = lane >> 4;
    const int b0 = blockIdx.x * 16;

    // zero only h1 buf1 (= h1(-1)); everything else written before first read
    for (int i = tid; i < 1024; i += 256) ((float*)h1p[1])[i] = 0.f;

    // ---- static weight fragments (A-operand), rows [16w,16w+16) ----
    const int mrow = 16 * w + n;
    const int m4 = 16 * w + 4 * q;
    short8 w0h[2], w0l[2], wi1h[2], wi1l[2], w1h[2], w1l[2];
    auto mkfrag = [&](const float* p, short8& hi, short8& lo) {
#pragma unroll
        for (int j = 0; j < 8; ++j) {
            const float v = p[j];
            const unsigned short h = f2bf(v);
            hi[j] = (short)h;
            lo[j] = (short)f2bf(v - bf2f(h));
        }
    };
#pragma unroll
    for (int k = 0; k < 2; ++k) {
        mkfrag(W_hh0 + mrow * 64 + 32 * k + 8 * q, w0h[k], w0l[k]);
        mkfrag(W_ih1 + mrow * 64 + 32 * k + 8 * q, wi1h[k], wi1l[k]);
        mkfrag(W_hh1 + mrow * 64 + 32 * k + 8 * q, w1h[k], w1l[k]);
    }
    const float4 wih0v = *(const float4*)(W_ih0 + m4);
    float4 bv0 = *(const float4*)(b_ih0 + m4);
    { float4 t = *(const float4*)(b_hh0 + m4); bv0.x += t.x; bv0.y += t.y; bv0.z += t.z; bv0.w += t.w; }
    float4 bv1 = *(const float4*)(b_ih1 + m4);
    { float4 t = *(const float4*)(b_hh1 + m4); bv1.x += t.x; bv1.y += t.y; bv1.z += t.z; bv1.w += t.w; }
    const float4 wfcv = *(const float4*)(W_fc + m4);

    const int rbase = 128 * q + 8 * n;
    const int wbase = (2 * w + (q >> 1)) * 128 + 8 * n + 4 * (q & 1);

    const float* xp = x + (long)(b0 + n) * TT;

    const floatx4 zero4 = {0.f, 0.f, 0.f, 0.f};

    // splitter: tanh + truncation split + pack, returns hi/lo uint2
    auto epi = [&](const floatx4& A, const floatx4& B, const floatx4& C,
                   uint2& hh, uint2& hl) {
        unsigned tb[4]; float lo[4];
#pragma unroll
        for (int r = 0; r < 4; ++r) {
            const float h = fast_tanh((A[r] + B[r]) + C[r]);
            tb[r] = __float_as_uint(h) & 0xffff0000u;
            lo[r] = h - __uint_as_float(tb[r]);
        }
        hh.x = __builtin_amdgcn_perm(tb[1], tb[0], 0x07060302u);
        hh.y = __builtin_amdgcn_perm(tb[3], tb[2], 0x07060302u);
        hl.x = __builtin_amdgcn_perm(__float_as_uint(lo[1]), __float_as_uint(lo[0]), 0x07060302u);
        hl.y = __builtin_amdgcn_perm(__float_as_uint(lo[3]), __float_as_uint(lo[2]), 0x07060302u);
    };

    // ---- pre-step s=0: h0(0) = tanh(x(0)*Wih0 + b0) -> buf 0 ----
    {
        const float xv = xp[0];
        unsigned tb[4]; float lo[4];
#pragma unroll
        for (int r = 0; r < 4; ++r) {
            const float h = fast_tanh(__builtin_fmaf(xv, f4e(wih0v, r), f4e(bv0, r)));
            tb[r] = __float_as_uint(h) & 0xffff0000u;
            lo[r] = h - __uint_as_float(tb[r]);
        }
        uint2 hh, hl;
        hh.x = __builtin_amdgcn_perm(tb[1], tb[0], 0x07060302u);
        hh.y = __builtin_amdgcn_perm(tb[3], tb[2], 0x07060302u);
        hl.x = __builtin_amdgcn_perm(__float_as_uint(lo[1]), __float_as_uint(lo[0]), 0x07060302u);
        hl.y = __builtin_amdgcn_perm(__float_as_uint(lo[3]), __float_as_uint(lo[2]), 0x07060302u);
        *(uint2*)&h0p[0][0][wbase] = hh;
        *(uint2*)&h0p[0][1][wbase] = hl;
    }
    __syncthreads();

    float xa = xp[1];  // x for next odd step
    float xb = xp[2];  // x for next even step

    // superstep body; rb0/wb0/rb1/wb1 must be literal constants at call site
    auto step = [&](int rb0, int wb0, int rb1, int wb1, float xv) {
        short8 bh[2], bl[2], ch[2], cl[2];
#pragma unroll
        for (int k = 0; k < 2; ++k) {
            bh[k] = *(const short8*)&h0p[rb0][0][rbase + 512 * k];
            bl[k] = *(const short8*)&h0p[rb0][1][rbase + 512 * k];
            ch[k] = *(const short8*)&h1p[rb1][0][rbase + 512 * k];
            cl[k] = *(const short8*)&h1p[rb1][1][rbase + 512 * k];
        }
        floatx4 a0A = {__builtin_fmaf(xv, wih0v.x, bv0.x), __builtin_fmaf(xv, wih0v.y, bv0.y),
                       __builtin_fmaf(xv, wih0v.z, bv0.z), __builtin_fmaf(xv, wih0v.w, bv0.w)};
        floatx4 a1A = {bv1.x, bv1.y, bv1.z, bv1.w};
        floatx4 a0B = zero4, a0C = zero4, a1B = zero4, a1C = zero4;
#pragma unroll
        for (int k = 0; k < 2; ++k) {
            a0A = __builtin_amdgcn_mfma_f32_16x16x32_bf16(w0h[k],  bh[k], a0A, 0, 0, 0);
            a1A = __builtin_amdgcn_mfma_f32_16x16x32_bf16(wi1h[k], bh[k], a1A, 0, 0, 0);
            a0B = __builtin_amdgcn_mfma_f32_16x16x32_bf16(w0h[k],  bl[k], a0B, 0, 0, 0);
            a1B = __builtin_amdgcn_mfma_f32_16x16x32_bf16(wi1h[k], bl[k], a1B, 0, 0, 0);
            a0C = __builtin_amdgcn_mfma_f32_16x16x32_bf16(w0l[k],  bh[k], a0C, 0, 0, 0);
            a1C = __builtin_amdgcn_mfma_f32_16x16x32_bf16(wi1l[k], bh[k], a1C, 0, 0, 0);
            a1A = __builtin_amdgcn_mfma_f32_16x16x32_bf16(w1h[k],  ch[k], a1A, 0, 0, 0);
            a1B = __builtin_amdgcn_mfma_f32_16x16x32_bf16(w1h[k],  cl[k], a1B, 0, 0, 0);
            a1C = __builtin_amdgcn_mfma_f32_16x16x32_bf16(w1l[k],  ch[k], a1C, 0, 0, 0);
        }
        // L0 epilogue + write FIRST (gets LDS writes in flight), then L1
        uint2 hh, hl;
        epi(a0A, a0B, a0C, hh, hl);
        *(uint2*)&h0p[wb0][0][wbase] = hh;
        *(uint2*)&h0p[wb0][1][wbase] = hl;
        epi(a1A, a1B, a1C, hh, hl);
        *(uint2*)&h1p[wb1][0][wbase] = hh;
        *(uint2*)&h1p[wb1][1][wbase] = hl;
        __syncthreads();
    };

    // pairs (s, s+1) for s = 1,3,...,509; then tail s=511
    for (int s = 1; s < 510; s += 2) {
        const float xva = xa; xa = xp[(s + 2) & (TT - 1)];
        step(0, 1, 1, 0, xva);                 // odd s
        const float xvb = xb; xb = xp[(s + 3) & (TT - 1)];
        step(1, 0, 0, 1, xvb);                 // even s+1
    }
    step(0, 1, 1, 0, xa);                      // s = 511

    // ---- post-step: h1(511) = tanh(Wi1·h0(511) + W1·h1(510) + b1) + FC dot ----
    float p;
    {
        short8 bh[2], bl[2], ch[2], cl[2];
#pragma unroll
        for (int k = 0; k < 2; ++k) {
            bh[k] = *(const short8*)&h0p[1][0][rbase + 512 * k];  // h0(511): buf 1
            bl[k] = *(const short8*)&h0p[1][1][rbase + 512 * k];
            ch[k] = *(const short8*)&h1p[0][0][rbase + 512 * k];  // h1(510): buf 0
            cl[k] = *(const short8*)&h1p[0][1][rbase + 512 * k];
        }
        floatx4 a1A = {bv1.x, bv1.y, bv1.z, bv1.w};
        floatx4 a1B = zero4, a1C = zero4;
#pragma unroll
        for (int k = 0; k < 2; ++k) {
            a1A = __builtin_amdgcn_mfma_f32_16x16x32_bf16(wi1h[k], bh[k], a1A, 0, 0, 0);
            a1B = __builtin_amdgcn_mfma_f32_16x16x32_bf16(wi1h[k], bl[k], a1B, 0, 0, 0);
            a1C = __builtin_amdgcn_mfma_f32_16x16x32_bf16(wi1l[k], bh[k], a1C, 0, 0, 0);
            a1A = __builtin_amdgcn_mfma_f32_16x16x32_bf16(w1h[k],  ch[k], a1A, 0, 0, 0);
            a1B = __builtin_amdgcn_mfma_f32_16x16x32_bf16(w1h[k],  cl[k], a1B, 0, 0, 0);
            a1C = __builtin_amdgcn_mfma_f32_16x16x32_bf16(w1l[k],  ch[k], a1C, 0, 0, 0);
        }
        p = 0.f;
#pragma unroll
        for (int r = 0; r < 4; ++r) {
            const float h = fast_tanh((a1A[r] + a1B[r]) + a1C[r]);
            p = __builtin_fmaf(h, f4e(wfcv, r), p);
        }
    }

    // ---- FC reduce across the 64 hidden rows ----
    p += __shfl_xor(p, 16, 64);
    p += __shfl_xor(p, 32, 64);
    if (lane < 16) red[w][lane] = p;
    __syncthreads();
    if (w == 0 && lane < 16)
        out[b0 + lane] = red[0][lane] + red[1][lane] + red[2][lane] + red[3][lane] + b_fc[0];
}

extern "C" void kernel_launch(void* const* d_in, const int* in_sizes, int n_in,
                              void* d_out, int out_size, void* d_ws, size_t ws_size,
                              hipStream_t stream) {
    const float* x     = (const float*)d_in[0];
    const float* W_ih0 = (const float*)d_in[1];
    const float* W_hh0 = (const float*)d_in[2];
    const float* b_ih0 = (const float*)d_in[3];
    const float* b_hh0 = (const float*)d_in[4];
    const float* W_ih1 = (const float*)d_in[5];
    const float* W_hh1 = (const float*)d_in[6];
    const float* b_ih1 = (const float*)d_in[7];
    const float* b_hh1 = (const float*)d_in[8];
    const float* W_fc  = (const float*)d_in[9];
    const float* b_fc  = (const float*)d_in[10];
    float* out = (float*)d_out;

    rnn2_mfma<<<128, 256, 0, stream>>>(x, W_ih0, W_hh0, b_ih0, b_hh0,
                                       W_ih1, W_hh1, b_ih1, b_hh1,
                                       W_fc, b_fc, out);
}